// Round 11
// baseline (270.627 us; speedup 1.0000x reference)
//
#include <hip/hip_runtime.h>
#include <cmath>

#define NCH   256
#define NPIX  3136
#define NB    32
#define SEV   7
#define INV_N (1.0f / 3136.0f)

typedef __attribute__((ext_vector_type(8)))  short bf16x8;
typedef __attribute__((ext_vector_type(4)))  float f32x4;
typedef __attribute__((ext_vector_type(16))) float f32x16;

// ws layout (float offsets) — unchanged
#define KV7_F  (SEV * NB * 8 * 1024)   // 1,835,008
#define KM7_F  (SEV * NB * 256)        // 57,344
#define KVF_F  (NB * 8 * 1024)         // 262,144
#define KMF_F  (NB * 256)              // 8,192
#define KM7_OFF (KV7_F)
#define KVF_OFF (KM7_OFF + KM7_F)
#define KMF_OFF (KVF_OFF + KVF_F)
#define WF_OFF  (KMF_OFF + KMF_F)      // ushort region (16B aligned)

__device__ __forceinline__ ushort f2bf(float f) {
  unsigned u = __float_as_uint(f);
  u += 0x7FFFu + ((u >> 16) & 1u);
  return (ushort)(u >> 16);
}
__device__ __forceinline__ float bf2f(ushort h) {
  return __uint_as_float(((unsigned)h) << 16);
}

// ---------------------------------------------------------------------------
// Prep: qk_w (512x128) -> MFMA A-fragment layout, bf16 hi/lo split.
// ---------------------------------------------------------------------------
__global__ void wfrag_kernel(const float* __restrict__ qk_w, ushort* __restrict__ Wf) {
  const int tid = blockIdx.x * 512 + threadIdx.x;   // 0..16383
  const int lane = tid & 63;
  const int ks = (tid >> 6) & 3;
  const int mt = (tid >> 8) & 15;
  const int hl = (tid >> 12) & 1;
  const int side = (tid >> 13) & 1;
  const int ch = mt * 16 + (lane & 15);
  const int oc = side * 256 + ch;
  ushort v[8];
#pragma unroll
  for (int j = 0; j < 8; ++j) {
    const int k = ks * 32 + (lane >> 4) * 8 + j;
    const float w = qk_w[(size_t)oc * 128 + k];
    const ushort hi = f2bf(w);
    v[j] = (hl == 0) ? hi : f2bf(w - bf2f(hi));
  }
  *(uint4*)(Wf + (size_t)tid * 8) = *(const uint4*)v;
}

// ---------------------------------------------------------------------------
// Kernel A (v11): head-split grid 448 = (hd, sev, b); 512 thr, 2 blocks/CU.
// Per block: 4 heads (hd*4..+4). Conv wave = one 16-ch Mtile (wf resident).
// Kst[128][88] and Vst[128][88] both [ch][pos] -> einsum A AND B are vector
// b128 LDS reads with full-bank-spread strides (176 B == 12 words mod 32).
// hd==1: V channels == conv input channels -> one staging pass feeds both.
// Einsum: 2 waves per head (pos halves), final LDS pair-reduce.
// ---------------------------------------------------------------------------
__global__ __launch_bounds__(512, 4)
void kv_kernel(const float* __restrict__ x, const ushort* __restrict__ Wf,
               const float* __restrict__ qk_b, float* __restrict__ kv7,
               float* __restrict__ km7) {
  const int bid = blockIdx.x;
  const int hd = (bid >= 224) ? 1 : 0;   // +224 -> same bid%8 -> same XCD pair
  const int rem = bid - hd * 224;
  const int sev = rem >> 5, b = rem & 31;
  const int t = threadIdx.x;
  const int w = t >> 6, l = t & 63;
  const int q = l >> 4, r15 = l & 15;    // conv frag coords
  const int e = l & 31, q5 = l >> 5;     // einsum frag coords
  const int h_l = w & 3, ph = w >> 2;    // einsum: head-local, pos-half
  const int mt = w;                      // conv: Mtile 0..7

  __shared__ __align__(16) ushort Xb[64][152];      // [pos][conv-in ch] 19.5 KB
  __shared__ __align__(16) ushort KVs[2 * 128 * 88];// Kst | Vst, 45 KB
  ushort (*Kst)[88] = (ushort(*)[88])KVs;
  ushort (*Vst)[88] = (ushort(*)[88])(KVs + 128 * 88);

  // resident W frags: side 1 (k-conv), global Mtile = hd*8 + mt
  bf16x8 wf[4][2];
#pragma unroll
  for (int ks = 0; ks < 4; ++ks)
#pragma unroll
    for (int hl = 0; hl < 2; ++hl) {
      const size_t off =
          (size_t)(((((2 + hl) * 16 + (hd * 8 + mt)) * 4 + ks) * 64 + l)) * 8;
      wf[ks][hl] = *(const bf16x8*)(Wf + off);
    }

  float bias[4];
#pragma unroll
  for (int r = 0; r < 4; ++r)
    bias[r] = qk_b[256 + hd * 128 + mt * 16 + q * 4 + r];

  f32x16 kvacc;
#pragma unroll
  for (int i = 0; i < 16; ++i) kvacc[i] = 0.f;
  float kmacc[4] = {0.f, 0.f, 0.f, 0.f};

  const float* xk = x + ((size_t)(b * NCH) + 128) * NPIX + sev * 448;  // conv in
  const float* xv = x + ((size_t)(b * NCH)) * NPIX + sev * 448;        // hd=0 V

  for (int st = 0; st < SEV; ++st) {
    const int p0 = st * 64;
    __syncthreads();   // previous subtile's einsum done with Kst/Vst/Xb

    // ---- stage conv input ch 128..255 -> Xb [pos][ch]; hd==1 also -> Vst ----
#pragma unroll
    for (int rr = 0; rr < 4; ++rr) {
      const int id = t + 512 * rr;
      const int cc = id >> 4;      // 0..127
      const int pf = id & 15;      // f4-pos
      const float4 v = *(const float4*)(xk + (size_t)cc * NPIX + p0 + pf * 4);
      const ushort b0 = f2bf(v.x), b1 = f2bf(v.y), b2 = f2bf(v.z), b3 = f2bf(v.w);
      Xb[pf * 4 + 0][cc] = b0;
      Xb[pf * 4 + 1][cc] = b1;
      Xb[pf * 4 + 2][cc] = b2;
      Xb[pf * 4 + 3][cc] = b3;
      if (hd == 1) {
        const uint2 pk = {(uint)b0 | ((uint)b1 << 16), (uint)b2 | ((uint)b3 << 16)};
        *(uint2*)&Vst[cc][pf * 4] = pk;
      }
    }
    if (hd == 0) {
      // V channels 0..127 -> Vst [ch][pos] (b64 packed writes)
#pragma unroll
      for (int rr = 0; rr < 4; ++rr) {
        const int id = t + 512 * rr;
        const int cc = id >> 4;
        const int pf = id & 15;
        const float4 v = *(const float4*)(xv + (size_t)cc * NPIX + p0 + pf * 4);
        const uint2 pk = {(uint)f2bf(v.x) | ((uint)f2bf(v.y) << 16),
                          (uint)f2bf(v.z) | ((uint)f2bf(v.w) << 16)};
        *(uint2*)&Vst[cc][pf * 4] = pk;
      }
    }
    __syncthreads();

    // ---- conv MFMA: 1 Mtile x 4 Ntiles x 4 ks x hi/lo ----
    f32x4 acc[4];
#pragma unroll
    for (int nt = 0; nt < 4; ++nt)
#pragma unroll
      for (int r = 0; r < 4; ++r) acc[nt][r] = 0.f;
#pragma unroll
    for (int ks = 0; ks < 4; ++ks) {
      bf16x8 xbf[4];
#pragma unroll
      for (int nt = 0; nt < 4; ++nt)
        xbf[nt] = *(const bf16x8*)&Xb[nt * 16 + r15][ks * 32 + q * 8];
#pragma unroll
      for (int nt = 0; nt < 4; ++nt) {
        acc[nt] = __builtin_amdgcn_mfma_f32_16x16x32_bf16(wf[ks][0], xbf[nt], acc[nt], 0, 0, 0);
        acc[nt] = __builtin_amdgcn_mfma_f32_16x16x32_bf16(wf[ks][1], xbf[nt], acc[nt], 0, 0, 0);
      }
    }

    // ---- epilogue: bias + elu+1, km reg-accumulate, Kst [ch][pos] writes ----
#pragma unroll
    for (int nt = 0; nt < 4; ++nt) {
#pragma unroll
      for (int r = 0; r < 4; ++r) {
        float v = acc[nt][r] + bias[r];
        v = (v > 0.f) ? (v + 1.f) : __expf(v);
        kmacc[r] += v;
        Kst[mt * 16 + q * 4 + r][nt * 16 + r15] = f2bf(v);
      }
    }
    __syncthreads();   // Kst complete for all waves

    // ---- kv einsum: wave (h_l, ph): 2 x mfma_32x32x16, both operands b128 ----
#pragma unroll
    for (int ks2 = 0; ks2 < 2; ++ks2) {
      const int kp = ph * 32 + ks2 * 16 + q5 * 8;
      const bf16x8 ak = *(const bf16x8*)&Kst[h_l * 32 + e][kp];
      const bf16x8 bv = *(const bf16x8*)&Vst[h_l * 32 + e][kp];
      kvacc = __builtin_amdgcn_mfma_f32_32x32x16_bf16(ak, bv, kvacc, 0, 0, 0);
    }
  }

  // ---- cross-wave (ph) pair-reduce via LDS alias, write kv7 partial ----
  __syncthreads();
  float* red = (float*)KVs;   // 32 KB needed, 45 KB available
#pragma unroll
  for (int reg = 0; reg < 16; ++reg) {
    const int row = (reg & 3) + 8 * (reg >> 2) + 4 * q5;
    red[w * 1024 + row * 32 + e] = kvacc[reg];
  }
  __syncthreads();
#pragma unroll
  for (int i = 0; i < 8; ++i) {
    const int idx = t + 512 * i;      // 0..4095
    const int hl2 = idx >> 10;
    const int el = idx & 1023;
    const float s = red[hl2 * 1024 + el] + red[(hl2 + 4) * 1024 + el];
    kv7[(((size_t)sev * NB + b) * 8 + hd * 4 + hl2) * 1024 + el] = s;
  }
  // km: shfl-reduce over the 16 pos-lanes, lane r15==0 writes
#pragma unroll
  for (int r = 0; r < 4; ++r) {
    float s = kmacc[r];
    s += __shfl_xor(s, 1);
    s += __shfl_xor(s, 2);
    s += __shfl_xor(s, 4);
    s += __shfl_xor(s, 8);
    if (r15 == 0)
      km7[((size_t)sev * NB + b) * 256 + hd * 128 + mt * 16 + q * 4 + r] = s;
  }
}

// ---------------------------------------------------------------------------
// Reduce: sum 7 partials, scale by 1/n.
// ---------------------------------------------------------------------------
__global__ void red_kernel(const float* __restrict__ kv7, const float* __restrict__ km7,
                           float* __restrict__ kvF, float* __restrict__ kmF) {
  const int b = blockIdx.x;
  const int t = threadIdx.x;
  for (int i = t; i < 8192; i += 256) {
    float s = 0.f;
#pragma unroll
    for (int sv = 0; sv < SEV; ++sv)
      s += kv7[(size_t)(sv * NB + b) * 8192 + i];
    kvF[(size_t)b * 8192 + i] = s * INV_N;
  }
  {
    float s = 0.f;
#pragma unroll
    for (int sv = 0; sv < SEV; ++sv)
      s += km7[(size_t)(sv * NB + b) * 256 + t];
    kmF[b * 256 + t] = s * INV_N;
  }
}

// ---------------------------------------------------------------------------
// pe taps: 3x3 depthwise window for 4 consecutive cols of one row (f32 exact).
// ---------------------------------------------------------------------------
__device__ __forceinline__ void pe_taps(const float* __restrict__ xc,
                                        const float* __restrict__ pw, float pb,
                                        int r, int cl, float pe[4]) {
  pe[0] = pb; pe[1] = pb; pe[2] = pb; pe[3] = pb;
#pragma unroll
  for (int dy = -1; dy <= 1; ++dy) {
    const int rr = r + dy;
    if (rr < 0 || rr >= 56) continue;
    const float* base = xc + rr * 56 + cl;
    const float4 cen = *(const float4*)base;
    const float lft = (cl > 0) ? base[-1] : 0.f;
    const float rgt = (cl < 52) ? base[4] : 0.f;
    const float w0 = pw[(dy + 1) * 3 + 0];
    const float w1 = pw[(dy + 1) * 3 + 1];
    const float w2 = pw[(dy + 1) * 3 + 2];
    pe[0] += w0 * lft   + w1 * cen.x + w2 * cen.y;
    pe[1] += w0 * cen.x + w1 * cen.y + w2 * cen.z;
    pe[2] += w0 * cen.y + w1 * cen.z + w2 * cen.w;
    pe[3] += w0 * cen.z + w1 * cen.w + w2 * rgt;
  }
}

// ---------------------------------------------------------------------------
// Kernel B: Q-conv via MFMA, num via 16x16x32 MFMA, den f32, pe FUSED into
// the store (x fits L3 -> taps are cache-served; kills the 206 MB out RMW).
// ---------------------------------------------------------------------------
__global__ __launch_bounds__(512, 2)
void out_kernel(const float* __restrict__ x, const ushort* __restrict__ Wf,
                const float* __restrict__ qk_b, const float* __restrict__ kvF,
                const float* __restrict__ kmF, const float* __restrict__ pe_w,
                const float* __restrict__ pe_b, float* __restrict__ out) {
  const int bid = blockIdx.x;
  const int b = bid & 31, sev = bid >> 5;
  const int t = threadIdx.x;
  const int wave = t >> 6, l = t & 63;
  const int q = l >> 4, r15 = l & 15;
  const int mw = wave & 3, ng = wave >> 2;
  const int h = wave;

  __shared__ ushort Xb[64][136];
  __shared__ ushort QT[64][264];
  __shared__ float denT[8][64];

  bf16x8 wf[4][4][2];
#pragma unroll
  for (int mti = 0; mti < 4; ++mti)
#pragma unroll
    for (int ks = 0; ks < 4; ++ks)
#pragma unroll
      for (int hl = 0; hl < 2; ++hl) {
        const size_t off =
            (size_t)((((hl * 16 + (mw * 4 + mti)) * 4 + ks) * 64 + l)) * 8;
        wf[mti][ks][hl] = *(const bf16x8*)(Wf + off);
      }

  float bias[4][4], kmw[4][4];
#pragma unroll
  for (int mti = 0; mti < 4; ++mti)
#pragma unroll
    for (int r = 0; r < 4; ++r) {
      const int c = (mw * 4 + mti) * 16 + q * 4 + r;
      bias[mti][r] = qk_b[c];
      kmw[mti][r] = kmF[b * 256 + c];
    }

  bf16x8 bkv[2];
#pragma unroll
  for (int eh = 0; eh < 2; ++eh) {
#pragma unroll
    for (int j = 0; j < 8; ++j)
      bkv[eh][j] = (short)f2bf(
          kvF[(size_t)b * 8192 + h * 1024 + (q * 8 + j) * 32 + eh * 16 + r15]);
  }

  // pe state for this thread's two output channels
  const int oc0 = h * 32 + r15;
  const int oc1 = oc0 + 16;
  float pw0[9], pw1[9];
#pragma unroll
  for (int i = 0; i < 9; ++i) {
    pw0[i] = pe_w[oc0 * 9 + i];
    pw1[i] = pe_w[oc1 * 9 + i];
  }
  const float pb0 = pe_b[oc0], pb1 = pe_b[oc1];
  const float* xc0 = x + ((size_t)(b * NCH + oc0)) * NPIX;
  const float* xc1 = x + ((size_t)(b * NCH + oc1)) * NPIX;

  const float* xq = x + (size_t)(b * NCH) * NPIX + sev * 448;

  for (int st = 0; st < SEV; ++st) {
    const int pos0 = st * 64;
#pragma unroll
    for (int rr = 0; rr < 4; ++rr) {
      const int id = t + 512 * rr;
      const int ch = id >> 4;
      const int p4 = (id & 15) * 4;
      const float4 v = *(const float4*)(xq + (size_t)ch * NPIX + pos0 + p4);
      Xb[p4 + 0][ch] = f2bf(v.x);
      Xb[p4 + 1][ch] = f2bf(v.y);
      Xb[p4 + 2][ch] = f2bf(v.z);
      Xb[p4 + 3][ch] = f2bf(v.w);
    }
    __syncthreads();

    f32x4 acc[4][2];
#pragma unroll
    for (int i = 0; i < 4; ++i)
#pragma unroll
      for (int nt = 0; nt < 2; ++nt)
#pragma unroll
        for (int r = 0; r < 4; ++r) acc[i][nt][r] = 0.f;
#pragma unroll
    for (int ks = 0; ks < 4; ++ks) {
      const bf16x8 xb0 = *(const bf16x8*)&Xb[(ng * 2 + 0) * 16 + r15][ks * 32 + q * 8];
      const bf16x8 xb1 = *(const bf16x8*)&Xb[(ng * 2 + 1) * 16 + r15][ks * 32 + q * 8];
#pragma unroll
      for (int mti = 0; mti < 4; ++mti) {
        acc[mti][0] = __builtin_amdgcn_mfma_f32_16x16x32_bf16(wf[mti][ks][0], xb0, acc[mti][0], 0, 0, 0);
        acc[mti][0] = __builtin_amdgcn_mfma_f32_16x16x32_bf16(wf[mti][ks][1], xb0, acc[mti][0], 0, 0, 0);
        acc[mti][1] = __builtin_amdgcn_mfma_f32_16x16x32_bf16(wf[mti][ks][0], xb1, acc[mti][1], 0, 0, 0);
        acc[mti][1] = __builtin_amdgcn_mfma_f32_16x16x32_bf16(wf[mti][ks][1], xb1, acc[mti][1], 0, 0, 0);
      }
    }

    float pdh[2][2];
    pdh[0][0] = pdh[0][1] = pdh[1][0] = pdh[1][1] = 0.f;
#pragma unroll
    for (int mti = 0; mti < 4; ++mti) {
#pragma unroll
      for (int nt = 0; nt < 2; ++nt) {
        ushort pk[4];
        float dsum = 0.f;
#pragma unroll
        for (int r = 0; r < 4; ++r) {
          float v = acc[mti][nt][r] + bias[mti][r];
          v = (v > 0.f) ? (v + 1.f) : __expf(v);
          pk[r] = f2bf(v);
          dsum += v * kmw[mti][r];
        }
        *(uint2*)&QT[(ng * 2 + nt) * 16 + r15][(mw * 4 + mti) * 16 + q * 4] =
            *(const uint2*)pk;
        pdh[mti >> 1][nt] += dsum;
      }
    }
#pragma unroll
    for (int ht = 0; ht < 2; ++ht)
#pragma unroll
      for (int nt = 0; nt < 2; ++nt) {
        float s = pdh[ht][nt];
        s += __shfl_xor(s, 16);
        s += __shfl_xor(s, 32);
        if (q == 0) denT[mw * 2 + ht][(ng * 2 + nt) * 16 + r15] = s;
      }
    __syncthreads();

#pragma unroll
    for (int pt = 0; pt < 4; ++pt) {
      const bf16x8 aq = *(const bf16x8*)&QT[pt * 16 + r15][h * 32 + q * 8];
      f32x4 z;
      z[0] = z[1] = z[2] = z[3] = 0.f;
      const f32x4 n0 = __builtin_amdgcn_mfma_f32_16x16x32_bf16(aq, bkv[0], z, 0, 0, 0);
      const f32x4 n1 = __builtin_amdgcn_mfma_f32_16x16x32_bf16(aq, bkv[1], z, 0, 0, 0);
      float rdn[4];
#pragma unroll
      for (int r = 0; r < 4; ++r)
        rdn[r] = 1.0f / (denT[h][pt * 16 + q * 4 + r] + 1e-6f);

      const int posg = sev * 448 + pos0 + pt * 16 + q * 4;
      const int rrow = posg / 56;
      const int cl = posg - rrow * 56;
      float pe0[4], pe1[4];
      pe_taps(xc0, pw0, pb0, rrow, cl, pe0);
      pe_taps(xc1, pw1, pb1, rrow, cl, pe1);

      float4 o0, o1;
      o0.x = n0[0] * rdn[0] + pe0[0]; o0.y = n0[1] * rdn[1] + pe0[1];
      o0.z = n0[2] * rdn[2] + pe0[2]; o0.w = n0[3] * rdn[3] + pe0[3];
      o1.x = n1[0] * rdn[0] + pe1[0]; o1.y = n1[1] * rdn[1] + pe1[1];
      o1.z = n1[2] * rdn[2] + pe1[2]; o1.w = n1[3] * rdn[3] + pe1[3];
      *(float4*)(out + ((size_t)(b * NCH + oc0)) * NPIX + posg) = o0;
      *(float4*)(out + ((size_t)(b * NCH + oc1)) * NPIX + posg) = o1;
    }
  }
}

extern "C" void kernel_launch(void* const* d_in, const int* in_sizes, int n_in,
                              void* d_out, int out_size, void* d_ws,
                              size_t ws_size, hipStream_t stream) {
  const float* x    = (const float*)d_in[0];
  const float* qk_w = (const float*)d_in[1];
  const float* qk_b = (const float*)d_in[2];
  const float* pe_w = (const float*)d_in[3];
  const float* pe_b = (const float*)d_in[4];
  float* out = (float*)d_out;

  float* wsf = (float*)d_ws;
  float* kv7 = wsf;
  float* km7 = wsf + KM7_OFF;
  float* kvF = wsf + KVF_OFF;
  float* kmF = wsf + KMF_OFF;
  ushort* Wf = (ushort*)(wsf + WF_OFF);

  wfrag_kernel<<<32, 512, 0, stream>>>(qk_w, Wf);
  kv_kernel<<<448, 512, 0, stream>>>(x, Wf, qk_b, kv7, km7);
  red_kernel<<<NB, 256, 0, stream>>>(kv7, km7, kvF, kmF);
  out_kernel<<<SEV * NB, 512, 0, stream>>>(x, Wf, qk_b, kvF, kmF, pe_w, pe_b, out);
}

// Round 12
// 166.209 us; speedup vs baseline: 1.6282x; 1.6282x over previous
//
#include <hip/hip_runtime.h>
#include <cmath>

#define NCH   256
#define NPIX  3136
#define NB    32
#define SEV   7
#define INV_N (1.0f / 3136.0f)

typedef __attribute__((ext_vector_type(8)))  short bf16x8;
typedef __attribute__((ext_vector_type(4)))  float f32x4;
typedef __attribute__((ext_vector_type(16))) float f32x16;

// ws layout (float offsets)
#define KV7_F  (SEV * NB * 8 * 1024)   // 1,835,008
#define KM7_F  (SEV * NB * 256)        // 57,344
#define KVF_F  (NB * 8 * 1024)         // 262,144
#define KMF_F  (NB * 256)              // 8,192
#define KM7_OFF (KV7_F)
#define KVF_OFF (KM7_OFF + KM7_F)
#define KMF_OFF (KVF_OFF + KVF_F)
#define WF_OFF  (KMF_OFF + KMF_F)      // ushort region (16B aligned)

__device__ __forceinline__ ushort f2bf(float f) {
  unsigned u = __float_as_uint(f);
  u += 0x7FFFu + ((u >> 16) & 1u);
  return (ushort)(u >> 16);
}
__device__ __forceinline__ float bf2f(ushort h) {
  return __uint_as_float(((unsigned)h) << 16);
}

// ---------------------------------------------------------------------------
// Prep: qk_w (512x128) -> MFMA A-fragment layout, bf16 hi/lo split.
// ---------------------------------------------------------------------------
__global__ void wfrag_kernel(const float* __restrict__ qk_w, ushort* __restrict__ Wf) {
  const int tid = blockIdx.x * 512 + threadIdx.x;   // 0..16383
  const int lane = tid & 63;
  const int ks = (tid >> 6) & 3;
  const int mt = (tid >> 8) & 15;
  const int hl = (tid >> 12) & 1;
  const int side = (tid >> 13) & 1;
  const int ch = mt * 16 + (lane & 15);
  const int oc = side * 256 + ch;
  ushort v[8];
#pragma unroll
  for (int j = 0; j < 8; ++j) {
    const int k = ks * 32 + (lane >> 4) * 8 + j;
    const float w = qk_w[(size_t)oc * 128 + k];
    const ushort hi = f2bf(w);
    v[j] = (hl == 0) ? hi : f2bf(w - bf2f(hi));
  }
  *(uint4*)(Wf + (size_t)tid * 8) = *(const uint4*)v;
}

// ---------------------------------------------------------------------------
// Kernel A (v11, validated ~35 us): head-split grid 448 = (hd, sev, b).
// Kst/Vst both [ch][pos] stride 88 -> einsum A AND B are b128 LDS reads.
// hd==1: V channels == conv input channels -> single staging pass.
// ---------------------------------------------------------------------------
__global__ __launch_bounds__(512, 4)
void kv_kernel(const float* __restrict__ x, const ushort* __restrict__ Wf,
               const float* __restrict__ qk_b, float* __restrict__ kv7,
               float* __restrict__ km7) {
  const int bid = blockIdx.x;
  const int hd = (bid >= 224) ? 1 : 0;
  const int rem = bid - hd * 224;
  const int sev = rem >> 5, b = rem & 31;
  const int t = threadIdx.x;
  const int w = t >> 6, l = t & 63;
  const int q = l >> 4, r15 = l & 15;
  const int e = l & 31, q5 = l >> 5;
  const int h_l = w & 3, ph = w >> 2;
  const int mt = w;

  __shared__ __align__(16) ushort Xb[64][152];
  __shared__ __align__(16) ushort KVs[2 * 128 * 88];
  ushort (*Kst)[88] = (ushort(*)[88])KVs;
  ushort (*Vst)[88] = (ushort(*)[88])(KVs + 128 * 88);

  bf16x8 wf[4][2];
#pragma unroll
  for (int ks = 0; ks < 4; ++ks)
#pragma unroll
    for (int hl = 0; hl < 2; ++hl) {
      const size_t off =
          (size_t)(((((2 + hl) * 16 + (hd * 8 + mt)) * 4 + ks) * 64 + l)) * 8;
      wf[ks][hl] = *(const bf16x8*)(Wf + off);
    }

  float bias[4];
#pragma unroll
  for (int r = 0; r < 4; ++r)
    bias[r] = qk_b[256 + hd * 128 + mt * 16 + q * 4 + r];

  f32x16 kvacc;
#pragma unroll
  for (int i = 0; i < 16; ++i) kvacc[i] = 0.f;
  float kmacc[4] = {0.f, 0.f, 0.f, 0.f};

  const float* xk = x + ((size_t)(b * NCH) + 128) * NPIX + sev * 448;
  const float* xv = x + ((size_t)(b * NCH)) * NPIX + sev * 448;

  for (int st = 0; st < SEV; ++st) {
    const int p0 = st * 64;
    __syncthreads();

#pragma unroll
    for (int rr = 0; rr < 4; ++rr) {
      const int id = t + 512 * rr;
      const int cc = id >> 4;
      const int pf = id & 15;
      const float4 v = *(const float4*)(xk + (size_t)cc * NPIX + p0 + pf * 4);
      const ushort b0 = f2bf(v.x), b1 = f2bf(v.y), b2 = f2bf(v.z), b3 = f2bf(v.w);
      Xb[pf * 4 + 0][cc] = b0;
      Xb[pf * 4 + 1][cc] = b1;
      Xb[pf * 4 + 2][cc] = b2;
      Xb[pf * 4 + 3][cc] = b3;
      if (hd == 1) {
        const uint2 pk = {(uint)b0 | ((uint)b1 << 16), (uint)b2 | ((uint)b3 << 16)};
        *(uint2*)&Vst[cc][pf * 4] = pk;
      }
    }
    if (hd == 0) {
#pragma unroll
      for (int rr = 0; rr < 4; ++rr) {
        const int id = t + 512 * rr;
        const int cc = id >> 4;
        const int pf = id & 15;
        const float4 v = *(const float4*)(xv + (size_t)cc * NPIX + p0 + pf * 4);
        const uint2 pk = {(uint)f2bf(v.x) | ((uint)f2bf(v.y) << 16),
                          (uint)f2bf(v.z) | ((uint)f2bf(v.w) << 16)};
        *(uint2*)&Vst[cc][pf * 4] = pk;
      }
    }
    __syncthreads();

    f32x4 acc[4];
#pragma unroll
    for (int nt = 0; nt < 4; ++nt)
#pragma unroll
      for (int r = 0; r < 4; ++r) acc[nt][r] = 0.f;
#pragma unroll
    for (int ks = 0; ks < 4; ++ks) {
      bf16x8 xbf[4];
#pragma unroll
      for (int nt = 0; nt < 4; ++nt)
        xbf[nt] = *(const bf16x8*)&Xb[nt * 16 + r15][ks * 32 + q * 8];
#pragma unroll
      for (int nt = 0; nt < 4; ++nt) {
        acc[nt] = __builtin_amdgcn_mfma_f32_16x16x32_bf16(wf[ks][0], xbf[nt], acc[nt], 0, 0, 0);
        acc[nt] = __builtin_amdgcn_mfma_f32_16x16x32_bf16(wf[ks][1], xbf[nt], acc[nt], 0, 0, 0);
      }
    }

#pragma unroll
    for (int nt = 0; nt < 4; ++nt) {
#pragma unroll
      for (int r = 0; r < 4; ++r) {
        float v = acc[nt][r] + bias[r];
        v = (v > 0.f) ? (v + 1.f) : __expf(v);
        kmacc[r] += v;
        Kst[mt * 16 + q * 4 + r][nt * 16 + r15] = f2bf(v);
      }
    }
    __syncthreads();

#pragma unroll
    for (int ks2 = 0; ks2 < 2; ++ks2) {
      const int kp = ph * 32 + ks2 * 16 + q5 * 8;
      const bf16x8 ak = *(const bf16x8*)&Kst[h_l * 32 + e][kp];
      const bf16x8 bv = *(const bf16x8*)&Vst[h_l * 32 + e][kp];
      kvacc = __builtin_amdgcn_mfma_f32_32x32x16_bf16(ak, bv, kvacc, 0, 0, 0);
    }
  }

  __syncthreads();
  float* red = (float*)KVs;
#pragma unroll
  for (int reg = 0; reg < 16; ++reg) {
    const int row = (reg & 3) + 8 * (reg >> 2) + 4 * q5;
    red[w * 1024 + row * 32 + e] = kvacc[reg];
  }
  __syncthreads();
#pragma unroll
  for (int i = 0; i < 8; ++i) {
    const int idx = t + 512 * i;
    const int hl2 = idx >> 10;
    const int el = idx & 1023;
    const float s = red[hl2 * 1024 + el] + red[(hl2 + 4) * 1024 + el];
    kv7[(((size_t)sev * NB + b) * 8 + hd * 4 + hl2) * 1024 + el] = s;
  }
#pragma unroll
  for (int r = 0; r < 4; ++r) {
    float s = kmacc[r];
    s += __shfl_xor(s, 1);
    s += __shfl_xor(s, 2);
    s += __shfl_xor(s, 4);
    s += __shfl_xor(s, 8);
    if (r15 == 0)
      km7[((size_t)sev * NB + b) * 256 + hd * 128 + mt * 16 + q * 4 + r] = s;
  }
}

// ---------------------------------------------------------------------------
// Reduce: sum 7 partials, scale by 1/n.
// ---------------------------------------------------------------------------
__global__ void red_kernel(const float* __restrict__ kv7, const float* __restrict__ km7,
                           float* __restrict__ kvF, float* __restrict__ kmF) {
  const int b = blockIdx.x;
  const int t = threadIdx.x;
  for (int i = t; i < 8192; i += 256) {
    float s = 0.f;
#pragma unroll
    for (int sv = 0; sv < SEV; ++sv)
      s += kv7[(size_t)(sv * NB + b) * 8192 + i];
    kvF[(size_t)b * 8192 + i] = s * INV_N;
  }
  {
    float s = 0.f;
#pragma unroll
    for (int sv = 0; sv < SEV; ++sv)
      s += km7[(size_t)(sv * NB + b) * 256 + t];
    kmF[b * 256 + t] = s * INV_N;
  }
}

// ---------------------------------------------------------------------------
// Kernel B (round-5/7 form, validated ~45 us): Q-conv via MFMA, num via
// 16x16x32 MFMA, den f32, f4 stores. NO pe.
// ---------------------------------------------------------------------------
__global__ __launch_bounds__(512, 2)
void out_kernel(const float* __restrict__ x, const ushort* __restrict__ Wf,
                const float* __restrict__ qk_b, const float* __restrict__ kvF,
                const float* __restrict__ kmF, float* __restrict__ out) {
  const int bid = blockIdx.x;
  const int b = bid & 31, sev = bid >> 5;
  const int t = threadIdx.x;
  const int wave = t >> 6, l = t & 63;
  const int q = l >> 4, r15 = l & 15;
  const int mw = wave & 3, ng = wave >> 2;
  const int h = wave;

  __shared__ ushort Xb[64][136];
  __shared__ ushort QT[64][264];
  __shared__ float denT[8][64];

  bf16x8 wf[4][4][2];
#pragma unroll
  for (int mti = 0; mti < 4; ++mti)
#pragma unroll
    for (int ks = 0; ks < 4; ++ks)
#pragma unroll
      for (int hl = 0; hl < 2; ++hl) {
        const size_t off =
            (size_t)((((hl * 16 + (mw * 4 + mti)) * 4 + ks) * 64 + l)) * 8;
        wf[mti][ks][hl] = *(const bf16x8*)(Wf + off);
      }

  float bias[4][4], kmw[4][4];
#pragma unroll
  for (int mti = 0; mti < 4; ++mti)
#pragma unroll
    for (int r = 0; r < 4; ++r) {
      const int c = (mw * 4 + mti) * 16 + q * 4 + r;
      bias[mti][r] = qk_b[c];
      kmw[mti][r] = kmF[b * 256 + c];
    }

  bf16x8 bkv[2];
#pragma unroll
  for (int eh = 0; eh < 2; ++eh) {
#pragma unroll
    for (int j = 0; j < 8; ++j)
      bkv[eh][j] = (short)f2bf(
          kvF[(size_t)b * 8192 + h * 1024 + (q * 8 + j) * 32 + eh * 16 + r15]);
  }

  const float* xq = x + (size_t)(b * NCH) * NPIX + sev * 448;

  for (int st = 0; st < SEV; ++st) {
    const int pos0 = st * 64;
#pragma unroll
    for (int rr = 0; rr < 4; ++rr) {
      const int id = t + 512 * rr;
      const int ch = id >> 4;
      const int p4 = (id & 15) * 4;
      const float4 v = *(const float4*)(xq + (size_t)ch * NPIX + pos0 + p4);
      Xb[p4 + 0][ch] = f2bf(v.x);
      Xb[p4 + 1][ch] = f2bf(v.y);
      Xb[p4 + 2][ch] = f2bf(v.z);
      Xb[p4 + 3][ch] = f2bf(v.w);
    }
    __syncthreads();

    f32x4 acc[4][2];
#pragma unroll
    for (int i = 0; i < 4; ++i)
#pragma unroll
      for (int nt = 0; nt < 2; ++nt)
#pragma unroll
        for (int r = 0; r < 4; ++r) acc[i][nt][r] = 0.f;
#pragma unroll
    for (int ks = 0; ks < 4; ++ks) {
      const bf16x8 xb0 = *(const bf16x8*)&Xb[(ng * 2 + 0) * 16 + r15][ks * 32 + q * 8];
      const bf16x8 xb1 = *(const bf16x8*)&Xb[(ng * 2 + 1) * 16 + r15][ks * 32 + q * 8];
#pragma unroll
      for (int mti = 0; mti < 4; ++mti) {
        acc[mti][0] = __builtin_amdgcn_mfma_f32_16x16x32_bf16(wf[mti][ks][0], xb0, acc[mti][0], 0, 0, 0);
        acc[mti][0] = __builtin_amdgcn_mfma_f32_16x16x32_bf16(wf[mti][ks][1], xb0, acc[mti][0], 0, 0, 0);
        acc[mti][1] = __builtin_amdgcn_mfma_f32_16x16x32_bf16(wf[mti][ks][0], xb1, acc[mti][1], 0, 0, 0);
        acc[mti][1] = __builtin_amdgcn_mfma_f32_16x16x32_bf16(wf[mti][ks][1], xb1, acc[mti][1], 0, 0, 0);
      }
    }

    float pdh[2][2];
    pdh[0][0] = pdh[0][1] = pdh[1][0] = pdh[1][1] = 0.f;
#pragma unroll
    for (int mti = 0; mti < 4; ++mti) {
#pragma unroll
      for (int nt = 0; nt < 2; ++nt) {
        ushort pk[4];
        float dsum = 0.f;
#pragma unroll
        for (int r = 0; r < 4; ++r) {
          float v = acc[mti][nt][r] + bias[mti][r];
          v = (v > 0.f) ? (v + 1.f) : __expf(v);
          pk[r] = f2bf(v);
          dsum += v * kmw[mti][r];
        }
        *(uint2*)&QT[(ng * 2 + nt) * 16 + r15][(mw * 4 + mti) * 16 + q * 4] =
            *(const uint2*)pk;
        pdh[mti >> 1][nt] += dsum;
      }
    }
#pragma unroll
    for (int ht = 0; ht < 2; ++ht)
#pragma unroll
      for (int nt = 0; nt < 2; ++nt) {
        float s = pdh[ht][nt];
        s += __shfl_xor(s, 16);
        s += __shfl_xor(s, 32);
        if (q == 0) denT[mw * 2 + ht][(ng * 2 + nt) * 16 + r15] = s;
      }
    __syncthreads();

#pragma unroll
    for (int pt = 0; pt < 4; ++pt) {
      const bf16x8 aq = *(const bf16x8*)&QT[pt * 16 + r15][h * 32 + q * 8];
      f32x4 z;
      z[0] = z[1] = z[2] = z[3] = 0.f;
      const f32x4 n0 = __builtin_amdgcn_mfma_f32_16x16x32_bf16(aq, bkv[0], z, 0, 0, 0);
      const f32x4 n1 = __builtin_amdgcn_mfma_f32_16x16x32_bf16(aq, bkv[1], z, 0, 0, 0);
      float4 o0, o1;
      float rdn[4];
#pragma unroll
      for (int r = 0; r < 4; ++r)
        rdn[r] = 1.0f / (denT[h][pt * 16 + q * 4 + r] + 1e-6f);
      o0.x = n0[0] * rdn[0]; o0.y = n0[1] * rdn[1];
      o0.z = n0[2] * rdn[2]; o0.w = n0[3] * rdn[3];
      o1.x = n1[0] * rdn[0]; o1.y = n1[1] * rdn[1];
      o1.z = n1[2] * rdn[2]; o1.w = n1[3] * rdn[3];
      const int posg = sev * 448 + pos0 + pt * 16 + q * 4;
      const int c0 = h * 32 + r15;
      const int c1 = h * 32 + 16 + r15;
      *(float4*)(out + ((size_t)(b * NCH + c0)) * NPIX + posg) = o0;
      *(float4*)(out + ((size_t)(b * NCH + c1)) * NPIX + posg) = o1;
    }
  }
}

// ---------------------------------------------------------------------------
// Kernel C (validated in round 10, ~52 us): depthwise 3x3 pe conv, out RMW.
// 512 threads: wave = (channel 0..3, row-half 0..1) -> 24 waves/CU.
// ---------------------------------------------------------------------------
__global__ __launch_bounds__(512, 4)
void pe_kernel(const float* __restrict__ x, const float* __restrict__ pe_w,
               const float* __restrict__ pe_b, float* __restrict__ out) {
  const int b = blockIdx.y;
  const int c0 = blockIdx.x * 4;
  const int t = threadIdx.x;
  const int wave = t >> 6;
  const int cl = wave & 3;
  const int rh = wave >> 2;
  const int lane = t & 63;

  __shared__ float xs[4][NPIX];   // 50 KB

#pragma unroll
  for (int cc = 0; cc < 4; ++cc) {
    const float4* src = (const float4*)(x + ((size_t)(b * NCH + c0 + cc)) * NPIX);
    float4* dst = (float4*)&xs[cc][0];
    for (int i = t; i < NPIX / 4; i += 512) dst[i] = src[i];
  }
  __syncthreads();

  const int c = c0 + cl;
  float pw[9];
#pragma unroll
  for (int i = 0; i < 9; ++i) pw[i] = pe_w[c * 9 + i];
  const float pb = pe_b[c];
  float* oc = out + ((size_t)(b * NCH + c)) * NPIX;
  const float* xc = xs[cl];

  if (lane < 56) {
    const bool hasL = (lane > 0), hasR = (lane < 55);
    for (int rg = 0; rg < 7; ++rg) {
      const int rbase = rh * 28 + rg * 4;
      float o[4];
#pragma unroll
      for (int k = 0; k < 4; ++k) o[k] = oc[(rbase + k) * 56 + lane];
#pragma unroll
      for (int k = 0; k < 4; ++k) {
        const int r = rbase + k;
        float s = pb;
#pragma unroll
        for (int dy = -1; dy <= 1; ++dy) {
          const int rr = r + dy;
          if (rr < 0 || rr >= 56) continue;   // wave-uniform
          const float* xrow = xc + rr * 56 + lane;
          if (hasL) s += pw[(dy + 1) * 3 + 0] * xrow[-1];
          s += pw[(dy + 1) * 3 + 1] * xrow[0];
          if (hasR) s += pw[(dy + 1) * 3 + 2] * xrow[1];
        }
        o[k] += s;
      }
#pragma unroll
      for (int k = 0; k < 4; ++k) oc[(rbase + k) * 56 + lane] = o[k];
    }
  }
}

extern "C" void kernel_launch(void* const* d_in, const int* in_sizes, int n_in,
                              void* d_out, int out_size, void* d_ws,
                              size_t ws_size, hipStream_t stream) {
  const float* x    = (const float*)d_in[0];
  const float* qk_w = (const float*)d_in[1];
  const float* qk_b = (const float*)d_in[2];
  const float* pe_w = (const float*)d_in[3];
  const float* pe_b = (const float*)d_in[4];
  float* out = (float*)d_out;

  float* wsf = (float*)d_ws;
  float* kv7 = wsf;
  float* km7 = wsf + KM7_OFF;
  float* kvF = wsf + KVF_OFF;
  float* kmF = wsf + KMF_OFF;
  ushort* Wf = (ushort*)(wsf + WF_OFF);

  wfrag_kernel<<<32, 512, 0, stream>>>(qk_w, Wf);
  kv_kernel<<<448, 512, 0, stream>>>(x, Wf, qk_b, kv7, km7);
  red_kernel<<<NB, 256, 0, stream>>>(kv7, km7, kvF, kmF);
  out_kernel<<<SEV * NB, 512, 0, stream>>>(x, Wf, qk_b, kvF, kmF, out);

  dim3 g3(64, NB);
  pe_kernel<<<g3, 512, 0, stream>>>(x, pe_w, pe_b, out);
}

// Round 13
// 151.165 us; speedup vs baseline: 1.7903x; 1.0995x over previous
//
#include <hip/hip_runtime.h>
#include <cmath>

#define NCH   256
#define NPIX  3136
#define NB    32
#define SEV   7
#define INV_N (1.0f / 3136.0f)

typedef __attribute__((ext_vector_type(8)))  short bf16x8;
typedef __attribute__((ext_vector_type(4)))  float f32x4;
typedef __attribute__((ext_vector_type(16))) float f32x16;

// ws layout (float offsets)
#define KV7_F  (SEV * NB * 8 * 1024)   // 1,835,008
#define KM7_F  (SEV * NB * 256)        // 57,344
#define KVF_F  (NB * 8 * 1024)         // 262,144
#define KMF_F  (NB * 256)              // 8,192
#define KM7_OFF (KV7_F)
#define KVF_OFF (KM7_OFF + KM7_F)
#define KMF_OFF (KVF_OFF + KVF_F)
#define WF_OFF  (KMF_OFF + KMF_F)      // ushort region (16B aligned)

__device__ __forceinline__ ushort f2bf(float f) {
  unsigned u = __float_as_uint(f);
  u += 0x7FFFu + ((u >> 16) & 1u);
  return (ushort)(u >> 16);
}
__device__ __forceinline__ float bf2f(ushort h) {
  return __uint_as_float(((unsigned)h) << 16);
}

// ---------------------------------------------------------------------------
// Prep: qk_w (512x128) -> MFMA A-fragment layout, bf16 hi/lo split.
// ---------------------------------------------------------------------------
__global__ void wfrag_kernel(const float* __restrict__ qk_w, ushort* __restrict__ Wf) {
  const int tid = blockIdx.x * 512 + threadIdx.x;   // 0..16383
  const int lane = tid & 63;
  const int ks = (tid >> 6) & 3;
  const int mt = (tid >> 8) & 15;
  const int hl = (tid >> 12) & 1;
  const int side = (tid >> 13) & 1;
  const int ch = mt * 16 + (lane & 15);
  const int oc = side * 256 + ch;
  ushort v[8];
#pragma unroll
  for (int j = 0; j < 8; ++j) {
    const int k = ks * 32 + (lane >> 4) * 8 + j;
    const float w = qk_w[(size_t)oc * 128 + k];
    const ushort hi = f2bf(w);
    v[j] = (hl == 0) ? hi : f2bf(w - bf2f(hi));
  }
  *(uint4*)(Wf + (size_t)tid * 8) = *(const uint4*)v;
}

// ---------------------------------------------------------------------------
// Kernel A (v11, validated ~35 us): head-split grid 448 = (hd, sev, b).
// ---------------------------------------------------------------------------
__global__ __launch_bounds__(512, 4)
void kv_kernel(const float* __restrict__ x, const ushort* __restrict__ Wf,
               const float* __restrict__ qk_b, float* __restrict__ kv7,
               float* __restrict__ km7) {
  const int bid = blockIdx.x;
  const int hd = (bid >= 224) ? 1 : 0;
  const int rem = bid - hd * 224;
  const int sev = rem >> 5, b = rem & 31;
  const int t = threadIdx.x;
  const int w = t >> 6, l = t & 63;
  const int q = l >> 4, r15 = l & 15;
  const int e = l & 31, q5 = l >> 5;
  const int h_l = w & 3, ph = w >> 2;
  const int mt = w;

  __shared__ __align__(16) ushort Xb[64][152];
  __shared__ __align__(16) ushort KVs[2 * 128 * 88];
  ushort (*Kst)[88] = (ushort(*)[88])KVs;
  ushort (*Vst)[88] = (ushort(*)[88])(KVs + 128 * 88);

  bf16x8 wf[4][2];
#pragma unroll
  for (int ks = 0; ks < 4; ++ks)
#pragma unroll
    for (int hl = 0; hl < 2; ++hl) {
      const size_t off =
          (size_t)(((((2 + hl) * 16 + (hd * 8 + mt)) * 4 + ks) * 64 + l)) * 8;
      wf[ks][hl] = *(const bf16x8*)(Wf + off);
    }

  float bias[4];
#pragma unroll
  for (int r = 0; r < 4; ++r)
    bias[r] = qk_b[256 + hd * 128 + mt * 16 + q * 4 + r];

  f32x16 kvacc;
#pragma unroll
  for (int i = 0; i < 16; ++i) kvacc[i] = 0.f;
  float kmacc[4] = {0.f, 0.f, 0.f, 0.f};

  const float* xk = x + ((size_t)(b * NCH) + 128) * NPIX + sev * 448;
  const float* xv = x + ((size_t)(b * NCH)) * NPIX + sev * 448;

  for (int st = 0; st < SEV; ++st) {
    const int p0 = st * 64;
    __syncthreads();

#pragma unroll
    for (int rr = 0; rr < 4; ++rr) {
      const int id = t + 512 * rr;
      const int cc = id >> 4;
      const int pf = id & 15;
      const float4 v = *(const float4*)(xk + (size_t)cc * NPIX + p0 + pf * 4);
      const ushort b0 = f2bf(v.x), b1 = f2bf(v.y), b2 = f2bf(v.z), b3 = f2bf(v.w);
      Xb[pf * 4 + 0][cc] = b0;
      Xb[pf * 4 + 1][cc] = b1;
      Xb[pf * 4 + 2][cc] = b2;
      Xb[pf * 4 + 3][cc] = b3;
      if (hd == 1) {
        const uint2 pk = {(uint)b0 | ((uint)b1 << 16), (uint)b2 | ((uint)b3 << 16)};
        *(uint2*)&Vst[cc][pf * 4] = pk;
      }
    }
    if (hd == 0) {
#pragma unroll
      for (int rr = 0; rr < 4; ++rr) {
        const int id = t + 512 * rr;
        const int cc = id >> 4;
        const int pf = id & 15;
        const float4 v = *(const float4*)(xv + (size_t)cc * NPIX + p0 + pf * 4);
        const uint2 pk = {(uint)f2bf(v.x) | ((uint)f2bf(v.y) << 16),
                          (uint)f2bf(v.z) | ((uint)f2bf(v.w) << 16)};
        *(uint2*)&Vst[cc][pf * 4] = pk;
      }
    }
    __syncthreads();

    f32x4 acc[4];
#pragma unroll
    for (int nt = 0; nt < 4; ++nt)
#pragma unroll
      for (int r = 0; r < 4; ++r) acc[nt][r] = 0.f;
#pragma unroll
    for (int ks = 0; ks < 4; ++ks) {
      bf16x8 xbf[4];
#pragma unroll
      for (int nt = 0; nt < 4; ++nt)
        xbf[nt] = *(const bf16x8*)&Xb[nt * 16 + r15][ks * 32 + q * 8];
#pragma unroll
      for (int nt = 0; nt < 4; ++nt) {
        acc[nt] = __builtin_amdgcn_mfma_f32_16x16x32_bf16(wf[ks][0], xbf[nt], acc[nt], 0, 0, 0);
        acc[nt] = __builtin_amdgcn_mfma_f32_16x16x32_bf16(wf[ks][1], xbf[nt], acc[nt], 0, 0, 0);
      }
    }

#pragma unroll
    for (int nt = 0; nt < 4; ++nt) {
#pragma unroll
      for (int r = 0; r < 4; ++r) {
        float v = acc[nt][r] + bias[r];
        v = (v > 0.f) ? (v + 1.f) : __expf(v);
        kmacc[r] += v;
        Kst[mt * 16 + q * 4 + r][nt * 16 + r15] = f2bf(v);
      }
    }
    __syncthreads();

#pragma unroll
    for (int ks2 = 0; ks2 < 2; ++ks2) {
      const int kp = ph * 32 + ks2 * 16 + q5 * 8;
      const bf16x8 ak = *(const bf16x8*)&Kst[h_l * 32 + e][kp];
      const bf16x8 bv = *(const bf16x8*)&Vst[h_l * 32 + e][kp];
      kvacc = __builtin_amdgcn_mfma_f32_32x32x16_bf16(ak, bv, kvacc, 0, 0, 0);
    }
  }

  __syncthreads();
  float* red = (float*)KVs;
#pragma unroll
  for (int reg = 0; reg < 16; ++reg) {
    const int row = (reg & 3) + 8 * (reg >> 2) + 4 * q5;
    red[w * 1024 + row * 32 + e] = kvacc[reg];
  }
  __syncthreads();
#pragma unroll
  for (int i = 0; i < 8; ++i) {
    const int idx = t + 512 * i;
    const int hl2 = idx >> 10;
    const int el = idx & 1023;
    const float s = red[hl2 * 1024 + el] + red[(hl2 + 4) * 1024 + el];
    kv7[(((size_t)sev * NB + b) * 8 + hd * 4 + hl2) * 1024 + el] = s;
  }
#pragma unroll
  for (int r = 0; r < 4; ++r) {
    float s = kmacc[r];
    s += __shfl_xor(s, 1);
    s += __shfl_xor(s, 2);
    s += __shfl_xor(s, 4);
    s += __shfl_xor(s, 8);
    if (r15 == 0)
      km7[((size_t)sev * NB + b) * 256 + hd * 128 + mt * 16 + q * 4 + r] = s;
  }
}

// ---------------------------------------------------------------------------
// Reduce: sum 7 partials, scale by 1/n.
// ---------------------------------------------------------------------------
__global__ void red_kernel(const float* __restrict__ kv7, const float* __restrict__ km7,
                           float* __restrict__ kvF, float* __restrict__ kmF) {
  const int b = blockIdx.x;
  const int t = threadIdx.x;
  for (int i = t; i < 8192; i += 256) {
    float s = 0.f;
#pragma unroll
    for (int sv = 0; sv < SEV; ++sv)
      s += kv7[(size_t)(sv * NB + b) * 8192 + i];
    kvF[(size_t)b * 8192 + i] = s * INV_N;
  }
  {
    float s = 0.f;
#pragma unroll
    for (int sv = 0; sv < SEV; ++sv)
      s += km7[(size_t)(sv * NB + b) * 256 + t];
    kmF[b * 256 + t] = s * INV_N;
  }
}

// ---------------------------------------------------------------------------
// Kernel B (v13): channel-half split, grid 448 = (hd, sev, b), 2 blocks/CU.
// Per block: 128 Q-channels (wave = 1 Mtile), 4 heads. wf 32 VGPR.
// ---------------------------------------------------------------------------
__global__ __launch_bounds__(512, 4)
void out_kernel(const float* __restrict__ x, const ushort* __restrict__ Wf,
                const float* __restrict__ qk_b, const float* __restrict__ kvF,
                const float* __restrict__ kmF, float* __restrict__ out) {
  const int bid = blockIdx.x;
  const int hd = (bid >= 224) ? 1 : 0;   // paired blocks share bid%8 -> XCD
  const int rem = bid - hd * 224;
  const int b = rem & 31, sev = rem >> 5;
  const int t = threadIdx.x;
  const int w = t >> 6, l = t & 63;
  const int q = l >> 4, r15 = l & 15;
  const int mt = w;                      // conv: Mtile (16 Q-channels)
  const int h_l = w & 3, eh = w >> 2;    // num: local head, e-half

  __shared__ ushort Xb[64][136];
  __shared__ ushort QT[64][136];         // [pos][q-ch local 0..127]
  __shared__ float denP[8][64];          // per-Mtile den partials

  // resident W frags: side 0 (q-conv), global Mtile = hd*8 + mt
  bf16x8 wf[4][2];
#pragma unroll
  for (int ks = 0; ks < 4; ++ks)
#pragma unroll
    for (int hl = 0; hl < 2; ++hl) {
      const size_t off =
          (size_t)((((hl * 16 + (hd * 8 + mt)) * 4 + ks) * 64 + l)) * 8;
      wf[ks][hl] = *(const bf16x8*)(Wf + off);
    }

  float bias[4], kmw[4];
#pragma unroll
  for (int r = 0; r < 4; ++r) {
    const int c = hd * 128 + mt * 16 + q * 4 + r;
    bias[r] = qk_b[c];
    kmw[r] = kmF[b * 256 + c];
  }

  // kv' B-frag for this wave's (head, e-half)
  bf16x8 bkv;
  {
    const int hg = hd * 4 + h_l;
#pragma unroll
    for (int j = 0; j < 8; ++j)
      bkv[j] = (short)f2bf(
          kvF[(size_t)b * 8192 + hg * 1024 + (q * 8 + j) * 32 + eh * 16 + r15]);
  }

  const float* xq = x + (size_t)(b * NCH) * NPIX + sev * 448;

  for (int st = 0; st < SEV; ++st) {
    const int pos0 = st * 64;
    // stage x ch 0..127 (Q-conv input) as [pos][ch] bf16
#pragma unroll
    for (int rr = 0; rr < 4; ++rr) {
      const int id = t + 512 * rr;
      const int ch = id >> 4;
      const int p4 = (id & 15) * 4;
      const float4 v = *(const float4*)(xq + (size_t)ch * NPIX + pos0 + p4);
      Xb[p4 + 0][ch] = f2bf(v.x);
      Xb[p4 + 1][ch] = f2bf(v.y);
      Xb[p4 + 2][ch] = f2bf(v.z);
      Xb[p4 + 3][ch] = f2bf(v.w);
    }
    __syncthreads();

    // conv MFMA: 1 Mtile x 4 Ntiles x 4 ks x hi/lo = 32 MFMA
    f32x4 acc[4];
#pragma unroll
    for (int nt = 0; nt < 4; ++nt)
#pragma unroll
      for (int r = 0; r < 4; ++r) acc[nt][r] = 0.f;
#pragma unroll
    for (int ks = 0; ks < 4; ++ks) {
      bf16x8 xbf[4];
#pragma unroll
      for (int nt = 0; nt < 4; ++nt)
        xbf[nt] = *(const bf16x8*)&Xb[nt * 16 + r15][ks * 32 + q * 8];
#pragma unroll
      for (int nt = 0; nt < 4; ++nt) {
        acc[nt] = __builtin_amdgcn_mfma_f32_16x16x32_bf16(wf[ks][0], xbf[nt], acc[nt], 0, 0, 0);
        acc[nt] = __builtin_amdgcn_mfma_f32_16x16x32_bf16(wf[ks][1], xbf[nt], acc[nt], 0, 0, 0);
      }
    }

    // epilogue: bias + elu+1 -> QT; den partials (f32 exact) -> denP
#pragma unroll
    for (int nt = 0; nt < 4; ++nt) {
      ushort pk[4];
      float dsum = 0.f;
#pragma unroll
      for (int r = 0; r < 4; ++r) {
        float v = acc[nt][r] + bias[r];
        v = (v > 0.f) ? (v + 1.f) : __expf(v);
        pk[r] = f2bf(v);
        dsum += v * kmw[r];
      }
      *(uint2*)&QT[nt * 16 + r15][mt * 16 + q * 4] = *(const uint2*)pk;
      // reduce dsum over the 4 q-lanes (bits 4,5) sharing (nt, r15)
      dsum += __shfl_xor(dsum, 16);
      dsum += __shfl_xor(dsum, 32);
      if (q == 0) denP[mt][nt * 16 + r15] = dsum;
    }
    __syncthreads();

    // num: wave (h_l, eh): 4 pt x 1 MFMA; den = denP[2h_l] + denP[2h_l+1]
#pragma unroll
    for (int pt = 0; pt < 4; ++pt) {
      const bf16x8 aq = *(const bf16x8*)&QT[pt * 16 + r15][h_l * 32 + q * 8];
      f32x4 z;
      z[0] = z[1] = z[2] = z[3] = 0.f;
      const f32x4 n0 = __builtin_amdgcn_mfma_f32_16x16x32_bf16(aq, bkv, z, 0, 0, 0);
      float4 o0;
      float rdn[4];
#pragma unroll
      for (int r = 0; r < 4; ++r) {
        const int pl = pt * 16 + q * 4 + r;
        rdn[r] = 1.0f / (denP[2 * h_l][pl] + denP[2 * h_l + 1][pl] + 1e-6f);
      }
      o0.x = n0[0] * rdn[0]; o0.y = n0[1] * rdn[1];
      o0.z = n0[2] * rdn[2]; o0.w = n0[3] * rdn[3];
      const int posg = sev * 448 + pos0 + pt * 16 + q * 4;
      const int c = hd * 128 + h_l * 32 + eh * 16 + r15;
      *(float4*)(out + ((size_t)(b * NCH + c)) * NPIX + posg) = o0;
    }
  }
}

// ---------------------------------------------------------------------------
// Kernel C (validated, ~50 us): depthwise 3x3 pe conv, out RMW.
// ---------------------------------------------------------------------------
__global__ __launch_bounds__(512, 4)
void pe_kernel(const float* __restrict__ x, const float* __restrict__ pe_w,
               const float* __restrict__ pe_b, float* __restrict__ out) {
  const int b = blockIdx.y;
  const int c0 = blockIdx.x * 4;
  const int t = threadIdx.x;
  const int wave = t >> 6;
  const int cl = wave & 3;
  const int rh = wave >> 2;
  const int lane = t & 63;

  __shared__ float xs[4][NPIX];   // 50 KB

#pragma unroll
  for (int cc = 0; cc < 4; ++cc) {
    const float4* src = (const float4*)(x + ((size_t)(b * NCH + c0 + cc)) * NPIX);
    float4* dst = (float4*)&xs[cc][0];
    for (int i = t; i < NPIX / 4; i += 512) dst[i] = src[i];
  }
  __syncthreads();

  const int c = c0 + cl;
  float pw[9];
#pragma unroll
  for (int i = 0; i < 9; ++i) pw[i] = pe_w[c * 9 + i];
  const float pb = pe_b[c];
  float* oc = out + ((size_t)(b * NCH + c)) * NPIX;
  const float* xc = xs[cl];

  if (lane < 56) {
    const bool hasL = (lane > 0), hasR = (lane < 55);
    for (int rg = 0; rg < 7; ++rg) {
      const int rbase = rh * 28 + rg * 4;
      float o[4];
#pragma unroll
      for (int k = 0; k < 4; ++k) o[k] = oc[(rbase + k) * 56 + lane];
#pragma unroll
      for (int k = 0; k < 4; ++k) {
        const int r = rbase + k;
        float s = pb;
#pragma unroll
        for (int dy = -1; dy <= 1; ++dy) {
          const int rr = r + dy;
          if (rr < 0 || rr >= 56) continue;   // wave-uniform
          const float* xrow = xc + rr * 56 + lane;
          if (hasL) s += pw[(dy + 1) * 3 + 0] * xrow[-1];
          s += pw[(dy + 1) * 3 + 1] * xrow[0];
          if (hasR) s += pw[(dy + 1) * 3 + 2] * xrow[1];
        }
        o[k] += s;
      }
#pragma unroll
      for (int k = 0; k < 4; ++k) oc[(rbase + k) * 56 + lane] = o[k];
    }
  }
}

extern "C" void kernel_launch(void* const* d_in, const int* in_sizes, int n_in,
                              void* d_out, int out_size, void* d_ws,
                              size_t ws_size, hipStream_t stream) {
  const float* x    = (const float*)d_in[0];
  const float* qk_w = (const float*)d_in[1];
  const float* qk_b = (const float*)d_in[2];
  const float* pe_w = (const float*)d_in[3];
  const float* pe_b = (const float*)d_in[4];
  float* out = (float*)d_out;

  float* wsf = (float*)d_ws;
  float* kv7 = wsf;
  float* km7 = wsf + KM7_OFF;
  float* kvF = wsf + KVF_OFF;
  float* kmF = wsf + KMF_OFF;
  ushort* Wf = (ushort*)(wsf + WF_OFF);

  wfrag_kernel<<<32, 512, 0, stream>>>(qk_w, Wf);
  kv_kernel<<<448, 512, 0, stream>>>(x, Wf, qk_b, kv7, km7);
  red_kernel<<<NB, 256, 0, stream>>>(kv7, km7, kvF, kmF);
  out_kernel<<<448, 512, 0, stream>>>(x, Wf, qk_b, kvF, kmF, out);

  dim3 g3(64, NB);
  pe_kernel<<<g3, 512, 0, stream>>>(x, pe_w, pe_b, out);
}